// Round 7
// baseline (321.040 us; speedup 1.0000x reference)
//
#include <hip/hip_runtime.h>

#define THRESH   0.7f
#define BASEU    0x3F333334u   // bit pattern of smallest float > 0.7f
#define NBINS    2048          // level-1 bins: (u-BASEU)>>12  (0.7..1.0 -> 1229 used)
#define NSUB     4096          // level-2: exact patterns within one level-1 bin
#define NTHREADS 256
#define MAXBLK   8192
#define NBLK_FB  1024          // fallback grid; must stay co-resident (spin syncs)

typedef __attribute__((ext_vector_type(4))) float f32x4;

struct Blk { float sum_lt; unsigned cnt_lt, cnt_eq, pad; };  // 16 B

struct Ws {
  Blk      blk[MAXBLK];
  double   sum_lt, sum_eq, prefix_sum;
  unsigned cnt_lt, cnt_eq;
  unsigned done;
  unsigned fin0, fin1, fin2, fin3;
  unsigned selBin, rank_r, prefix_cnt;
  unsigned Hcnt[NBINS];
  float    Hsum[NBINS];
  unsigned subCnt[NSUB];
  float    subSum[NSUB];   // also probe dump area (common path never reads it)
};

// t is exactly 0.0 or 1.0 -> BCE collapses to one log; torch clamps log at -100.
__device__ __forceinline__ float bce_loss(float p, float t) {
  float x = (t > 0.5f) ? p : (1.0f - p);
  return fminf(-__logf(x), 100.0f);
}

// =================== K1: streaming pass (R6 shape, -s_eq, NT loads) =========
__global__ void k_main(
    const f32x4* __restrict__ p4, const f32x4* __restrict__ t4,
    Ws* __restrict__ ws, int n) {
  const int nvec = n >> 2;
  const int tid = blockIdx.x * NTHREADS + threadIdx.x;
  const int stride = gridDim.x * NTHREADS;

  float s_lt = 0.f;
  unsigned c_lt = 0u, c_eq = 0u;

  for (int i = tid; i < nvec; i += stride) {
    f32x4 p = __builtin_nontemporal_load(p4 + i);
    f32x4 t = __builtin_nontemporal_load(t4 + i);
#pragma unroll
    for (int c = 0; c < 4; ++c) {
      float pv = p[c];
      float x  = (t[c] > 0.5f) ? pv : (1.0f - pv);
      float l  = fminf(-__logf(x), 100.0f);
      bool lt  = (pv <  THRESH);
      s_lt += lt ? l : 0.0f;          // branchless: cndmask + add
      c_lt += lt ? 1u : 0u;
      c_eq += (pv == THRESH) ? 1u : 0u;
    }
  }
  // scalar tail (n % 4) -- eq-loss not needed here either (fallback rescans)
  {
    int i = (nvec << 2) + tid;
    if (i < n) {
      float pv = ((const float*)p4)[i];
      float l = bce_loss(pv, ((const float*)t4)[i]);
      if (pv < THRESH) { c_lt++; s_lt += l; }
      else if (pv == THRESH) { c_eq++; }
    }
  }

  // wave(64) reduce then block reduce, plain 16-B store (no atomics, no fence)
#pragma unroll
  for (int off = 32; off > 0; off >>= 1) {
    s_lt += __shfl_down(s_lt, off);
    c_lt += __shfl_down(c_lt, off);
    c_eq += __shfl_down(c_eq, off);
  }
  __shared__ float    red_slt[4];
  __shared__ unsigned red_clt[4], red_ceq[4];
  int wave = threadIdx.x >> 6;
  if ((threadIdx.x & 63) == 0) {
    red_slt[wave] = s_lt; red_clt[wave] = c_lt; red_ceq[wave] = c_eq;
  }
  __syncthreads();
  if (threadIdx.x == 0) {
    Blk b;
    b.sum_lt = red_slt[0] + red_slt[1] + red_slt[2] + red_slt[3];
    b.cnt_lt = red_clt[0] + red_clt[1] + red_clt[2] + red_clt[3];
    b.cnt_eq = red_ceq[0] + red_ceq[1] + red_ceq[2] + red_ceq[3];
    b.pad = 0u;
    ws->blk[blockIdx.x] = b;
  }
}

// ======= K2: cross-block reduce + decision + fallback-counter init ==========
__global__ __launch_bounds__(1024) void k_decide(
    float* __restrict__ out, Ws* __restrict__ ws, int nblk, int kidx) {
  double s_lt = 0.0;
  unsigned long long c_lt = 0, c_eq = 0;
  for (int i = threadIdx.x; i < nblk; i += 1024) {
    Blk b = ws->blk[i];
    s_lt += (double)b.sum_lt;
    c_lt += b.cnt_lt; c_eq += b.cnt_eq;
  }
#pragma unroll
  for (int off = 32; off > 0; off >>= 1) {
    s_lt += __shfl_down(s_lt, off);
    c_lt += __shfl_down(c_lt, off);
    c_eq += __shfl_down(c_eq, off);
  }
  __shared__ double rs[16];
  __shared__ unsigned long long rc[16], re[16];
  int wave = threadIdx.x >> 6;
  if ((threadIdx.x & 63) == 0) { rs[wave] = s_lt; rc[wave] = c_lt; re[wave] = c_eq; }
  __syncthreads();
  if (threadIdx.x == 0) {
    double slt = 0.0; unsigned long long clt = 0, ceq = 0;
    for (int w = 0; w < 16; ++w) { slt += rs[w]; clt += rc[w]; ceq += re[w]; }
    ws->sum_lt = slt; ws->sum_eq = 0.0;   // eq-losses filled by fallback P1 if needed
    ws->cnt_lt = (unsigned)clt; ws->cnt_eq = (unsigned)ceq;
    ws->fin0 = 0u; ws->fin1 = 0u; ws->fin2 = 0u; ws->fin3 = 0u;
    // p_sorted[k] <= 0.7f  <=>  count(p <= 0.7f) > k  => threshold = 0.7f
    if (clt + ceq > (unsigned long long)kidx) {
      out[0] = (float)(slt / (double)clt);
      ws->done = 1u;
    } else {
      ws->done = 0u;
    }
  }
}

// ================= K3: exact fallback, single kernel, spin-synced ===========
// Rare path (threshold > 0.7). NBLK_FB=1024 blocks, 32 KB LDS -> 5 blocks/CU
// -> 1280 co-resident >= 1024: spins cannot deadlock.
__device__ void gsync(unsigned* ctr, unsigned goal) {
  __syncthreads();
  if (threadIdx.x == 0) {
    __threadfence();
    atomicAdd(ctr, 1u);
    while (atomicAdd(ctr, 0u) < goal) __builtin_amdgcn_s_sleep(8);
  }
  __syncthreads();
  __threadfence();
}

__global__ __launch_bounds__(NTHREADS) void k_fallback(
    const float* __restrict__ pred, const float* __restrict__ targ,
    float* __restrict__ out, Ws* __restrict__ ws, int n, int kidx) {
  if (ws->done) return;   // common case: one load per block and out

  __shared__ union {
    struct { unsigned hc[NBINS]; float hs[NBINS]; } l1;
    struct { unsigned sc[NSUB];  float ss[NSUB];  } l2;
  } sh;
  __shared__ float sh_eq;

  const int gtid = blockIdx.x * NTHREADS + threadIdx.x;
  const int gstride = gridDim.x * NTHREADS;

  // ---- P0: zero global fallback arrays ----
  for (int i = gtid; i < NBINS; i += gstride) { ws->Hcnt[i] = 0u; ws->Hsum[i] = 0.f; }
  for (int i = gtid; i < NSUB;  i += gstride) { ws->subCnt[i] = 0u; ws->subSum[i] = 0.f; }
  gsync(&ws->fin0, gridDim.x);

  // ---- P1: level-1 histogram of p > 0.7 (+ eq-loss accumulation) ----
  for (int i = threadIdx.x; i < NBINS; i += NTHREADS) { sh.l1.hc[i] = 0u; sh.l1.hs[i] = 0.f; }
  if (threadIdx.x == 0) sh_eq = 0.f;
  __syncthreads();
  for (int i = gtid; i < n; i += gstride) {
    float pv = pred[i];
    if (pv >= THRESH) {
      float l = bce_loss(pv, targ[i]);
      if (pv == THRESH) {
        atomicAdd(&sh_eq, l);        // eq elements are kept in fallback (thr>0.7)
      } else {
        unsigned b = (__float_as_uint(pv) - BASEU) >> 12;
        if (b > NBINS - 1) b = NBINS - 1;
        atomicAdd(&sh.l1.hc[b], 1u);
        atomicAdd(&sh.l1.hs[b], l);
      }
    }
  }
  __syncthreads();
  for (int i = threadIdx.x; i < NBINS; i += NTHREADS) {
    if (sh.l1.hc[i])        atomicAdd(&ws->Hcnt[i], sh.l1.hc[i]);
    if (sh.l1.hs[i] != 0.f) atomicAdd(&ws->Hsum[i], sh.l1.hs[i]);
  }
  if (threadIdx.x == 0 && sh_eq != 0.f) atomicAdd(&ws->sum_eq, (double)sh_eq);
  gsync(&ws->fin1, gridDim.x);

  // ---- P2: block 0 selects the level-1 bin containing rank kidx ----
  if (blockIdx.x == 0 && threadIdx.x == 0) {
    unsigned long long cum = (unsigned long long)ws->cnt_lt + ws->cnt_eq;
    double csum = ws->sum_lt + ws->sum_eq;
    for (int b = 0; b < NBINS; ++b) {
      unsigned hcnt = atomicAdd(&ws->Hcnt[b], 0u);
      if (cum + hcnt > (unsigned long long)kidx) {
        atomicExch(&ws->selBin, (unsigned)b);
        atomicExch(&ws->rank_r, (unsigned)((unsigned long long)kidx - cum));
        atomicExch(&ws->prefix_cnt, (unsigned)cum);
        ws->prefix_sum = csum;
        break;
      }
      cum  += hcnt;
      csum += (double)atomicAdd(&ws->Hsum[b], 0.f);
    }
  }
  gsync(&ws->fin2, gridDim.x);

  // ---- P3: level-2 exact-pattern histogram within selected bin ----
  unsigned base = BASEU + (atomicAdd(&ws->selBin, 0u) << 12);
  for (int i = threadIdx.x; i < NSUB; i += NTHREADS) { sh.l2.sc[i] = 0u; sh.l2.ss[i] = 0.f; }
  __syncthreads();
  for (int i = gtid; i < n; i += gstride) {
    unsigned u = __float_as_uint(pred[i]);
    if (u >= base && u < base + NSUB) {
      atomicAdd(&sh.l2.sc[u - base], 1u);
      atomicAdd(&sh.l2.ss[u - base], bce_loss(pred[i], targ[i]));
    }
  }
  __syncthreads();
  for (int i = threadIdx.x; i < NSUB; i += NTHREADS) {
    if (sh.l2.sc[i])         atomicAdd(&ws->subCnt[i], sh.l2.sc[i]);
    if (sh.l2.ss[i] != 0.f)  atomicAdd(&ws->subSum[i], sh.l2.ss[i]);
  }
  gsync(&ws->fin3, gridDim.x);

  // ---- P4: block 0 finalizes ----
  if (blockIdx.x == 0 && threadIdx.x == 0) {
    unsigned r = atomicAdd(&ws->rank_r, 0u);
    unsigned long long cum = 0;
    double csum = 0.0;
    for (int i = 0; i < NSUB; ++i) {
      unsigned c = atomicAdd(&ws->subCnt[i], 0u);
      if (cum + c > (unsigned long long)r) {
        unsigned long long cnt_final = (unsigned long long)atomicAdd(&ws->prefix_cnt, 0u) + cum;
        double sum_final = ws->prefix_sum + csum;
        out[0] = (float)(sum_final / (double)cnt_final);
        break;
      }
      cum  += c;
      csum += (double)atomicAdd(&ws->subSum[i], 0.f);
    }
  }
}

// =============== DIAGNOSTIC PROBES (rocprof-visible ablations) ==============
// k_probe1: single-stream read ceiling. k_probe2: dual-stream paired read
// ceiling (k_main's exact access pattern, no log/accum structure).
__global__ void k_probe1(const f32x4* __restrict__ p4, Ws* __restrict__ ws, int nvec) {
  const int tid = blockIdx.x * NTHREADS + threadIdx.x;
  const int stride = gridDim.x * NTHREADS;
  f32x4 acc = {0.f, 0.f, 0.f, 0.f};
  for (int i = tid; i < nvec; i += stride) acc += p4[i];
  float s = acc.x + acc.y + acc.z + acc.w;
#pragma unroll
  for (int off = 32; off > 0; off >>= 1) s += __shfl_down(s, off);
  if (threadIdx.x == 0) ws->subSum[blockIdx.x & (NSUB - 1)] = s;  // keep live
}

__global__ void k_probe2(const f32x4* __restrict__ p4, const f32x4* __restrict__ t4,
                         Ws* __restrict__ ws, int nvec) {
  const int tid = blockIdx.x * NTHREADS + threadIdx.x;
  const int stride = gridDim.x * NTHREADS;
  f32x4 acc = {0.f, 0.f, 0.f, 0.f};
  for (int i = tid; i < nvec; i += stride) acc += p4[i] + t4[i];
  float s = acc.x + acc.y + acc.z + acc.w;
#pragma unroll
  for (int off = 32; off > 0; off >>= 1) s += __shfl_down(s, off);
  if (threadIdx.x == 0) ws->subCnt[blockIdx.x & (NSUB - 1)] = __float_as_uint(s);
}

extern "C" void kernel_launch(void* const* d_in, const int* in_sizes, int n_in,
                              void* d_out, int out_size, void* d_ws, size_t ws_size,
                              hipStream_t stream) {
  const float* pred = (const float*)d_in[0];
  const float* targ = (const float*)d_in[1];
  float* out = (float*)d_out;
  Ws* ws = (Ws*)d_ws;
  int n = in_sizes[0];
  // min_kept = min(int(0.5*(n-1)), n-1); trunc == floor for positive n
  long long kll = (long long)(n - 1) / 2;
  if (kll > (long long)(n - 1)) kll = n - 1;
  int kidx = (int)kll;

  int nvec = n >> 2;
  int nblk = (nvec + NTHREADS - 1) / NTHREADS;
  if (nblk > MAXBLK) nblk = MAXBLK;
  if (nblk < 1) nblk = 1;

  k_main    <<<nblk, NTHREADS, 0, stream>>>((const f32x4*)pred, (const f32x4*)targ, ws, n);
  k_decide  <<<1, 1024, 0, stream>>>(out, ws, nblk, kidx);
  k_fallback<<<NBLK_FB, NTHREADS, 0, stream>>>(pred, targ, out, ws, n, kidx);
  // diagnostics last (do not affect out)
  k_probe1  <<<nblk, NTHREADS, 0, stream>>>((const f32x4*)pred, ws, nvec);
  k_probe2  <<<nblk, NTHREADS, 0, stream>>>((const f32x4*)pred, (const f32x4*)targ, ws, nvec);
}

// Round 8
// 279.722 us; speedup vs baseline: 1.1477x; 1.1477x over previous
//
#include <hip/hip_runtime.h>

#define THRESH   0.7f
#define BASEU    0x3F333334u   // bit pattern of smallest float > 0.7f
#define NBINS    2048          // level-1 bins: (u-BASEU)>>12  (0.7..1.0 -> 1229 used)
#define NSUB     4096          // level-2: exact patterns within one level-1 bin
#define NTHREADS 256
#define UNR      8             // f32x4 per stream per thread; 16 loads in flight
#define MAXBLK   8192
#define NBLK_FB  1024          // fallback grid; must stay co-resident (spin syncs)
#define LOG2CLAMP 144.2695040888963f   // 100/ln2: clamp in log2 domain
#define LN2_HI   0.6931471805599453    // double, applied once in k_decide

typedef __attribute__((ext_vector_type(4))) float f32x4;

struct Blk { float sum_lt; unsigned cnt_lt, cnt_eq, pad; };  // 16 B

struct Ws {
  Blk      blk[MAXBLK];
  double   sum_lt, sum_eq, prefix_sum;
  unsigned cnt_lt, cnt_eq;
  unsigned done;
  unsigned fin0, fin1, fin2, fin3;
  unsigned selBin, rank_r, prefix_cnt;
  unsigned Hcnt[NBINS];
  float    Hsum[NBINS];
  unsigned subCnt[NSUB];
  float    subSum[NSUB];
};

// t is exactly 0.0 or 1.0 -> BCE collapses to one log; torch clamps log at -100.
// (ln-domain version, used by fallback path only)
__device__ __forceinline__ float bce_loss(float p, float t) {
  float x = (t > 0.5f) ? p : (1.0f - p);
  return fminf(-__logf(x), 100.0f);
}

// =================== K1: max-MLP streaming pass =============================
// 16 float4 loads (256 B) in flight per thread before any consume; the empty
// asm pins all 16 live so the compiler cannot sink/recycle (R3's failure).
// Accumulate -log2(x) clamped at 100/ln2; k_decide converts via *ln2.
__global__ void k_main(
    const f32x4* __restrict__ p4, const f32x4* __restrict__ t4,
    Ws* __restrict__ ws, int n) {
  const int nvec = n >> 2;
  const int i0 = blockIdx.x * (NTHREADS * UNR) + threadIdx.x;

  float s_lt = 0.f;
  unsigned c_lt = 0u, c_eq = 0u;

#define CONS(PV, TV)                                                           \
  _Pragma("unroll") for (int c = 0; c < 4; ++c) {                              \
    float pv = (PV)[c];                                                        \
    float xx = ((TV)[c] > 0.5f) ? pv : (1.0f - pv);                            \
    float l2 = fminf(-__log2f(xx), LOG2CLAMP);                                 \
    bool lt  = (pv < THRESH);                                                  \
    s_lt += lt ? l2 : 0.0f;                                                    \
    c_lt += lt ? 1u : 0u;                                                      \
    c_eq += (pv == THRESH) ? 1u : 0u;                                          \
  }

  if (i0 + (UNR - 1) * NTHREADS < nvec) {        // full block: no guards
    f32x4 pv0 = p4[i0 + 0 * NTHREADS], pv1 = p4[i0 + 1 * NTHREADS],
          pv2 = p4[i0 + 2 * NTHREADS], pv3 = p4[i0 + 3 * NTHREADS],
          pv4 = p4[i0 + 4 * NTHREADS], pv5 = p4[i0 + 5 * NTHREADS],
          pv6 = p4[i0 + 6 * NTHREADS], pv7 = p4[i0 + 7 * NTHREADS];
    f32x4 tv0 = t4[i0 + 0 * NTHREADS], tv1 = t4[i0 + 1 * NTHREADS],
          tv2 = t4[i0 + 2 * NTHREADS], tv3 = t4[i0 + 3 * NTHREADS],
          tv4 = t4[i0 + 4 * NTHREADS], tv5 = t4[i0 + 5 * NTHREADS],
          tv6 = t4[i0 + 6 * NTHREADS], tv7 = t4[i0 + 7 * NTHREADS];
    // Pin: all 16 loads issued & results live before any consumption.
    asm volatile("" ::
        "v"(pv0), "v"(pv1), "v"(pv2), "v"(pv3),
        "v"(pv4), "v"(pv5), "v"(pv6), "v"(pv7),
        "v"(tv0), "v"(tv1), "v"(tv2), "v"(tv3),
        "v"(tv4), "v"(tv5), "v"(tv6), "v"(tv7));
    CONS(pv0, tv0) CONS(pv1, tv1) CONS(pv2, tv2) CONS(pv3, tv3)
    CONS(pv4, tv4) CONS(pv5, tv5) CONS(pv6, tv6) CONS(pv7, tv7)
  } else {                                        // ragged last block
#pragma unroll
    for (int u = 0; u < UNR; ++u) {
      int id = i0 + u * NTHREADS;
      if (id < nvec) {
        f32x4 p = p4[id];
        f32x4 t = t4[id];
        CONS(p, t)
      }
    }
    // scalar tail (n % 4)
    int i = (nvec << 2) + threadIdx.x;
    if (blockIdx.x == gridDim.x - 1 && i < n) {
      float pv = ((const float*)p4)[i];
      float tv = ((const float*)t4)[i];
      float xx = (tv > 0.5f) ? pv : (1.0f - pv);
      float l2 = fminf(-__log2f(xx), LOG2CLAMP);
      if (pv < THRESH)       { c_lt++; s_lt += l2; }
      else if (pv == THRESH) { c_eq++; }
    }
  }
#undef CONS

  // wave(64) reduce then block reduce, plain 16-B store (no atomics, no fence)
#pragma unroll
  for (int off = 32; off > 0; off >>= 1) {
    s_lt += __shfl_down(s_lt, off);
    c_lt += __shfl_down(c_lt, off);
    c_eq += __shfl_down(c_eq, off);
  }
  __shared__ float    red_slt[4];
  __shared__ unsigned red_clt[4], red_ceq[4];
  int wave = threadIdx.x >> 6;
  if ((threadIdx.x & 63) == 0) {
    red_slt[wave] = s_lt; red_clt[wave] = c_lt; red_ceq[wave] = c_eq;
  }
  __syncthreads();
  if (threadIdx.x == 0) {
    Blk b;
    b.sum_lt = red_slt[0] + red_slt[1] + red_slt[2] + red_slt[3];
    b.cnt_lt = red_clt[0] + red_clt[1] + red_clt[2] + red_clt[3];
    b.cnt_eq = red_ceq[0] + red_ceq[1] + red_ceq[2] + red_ceq[3];
    b.pad = 0u;
    ws->blk[blockIdx.x] = b;
  }
}

// ======= K2: cross-block reduce + decision + fallback-counter init ==========
__global__ __launch_bounds__(1024) void k_decide(
    float* __restrict__ out, Ws* __restrict__ ws, int nblk, int kidx) {
  double s_lt = 0.0;
  unsigned long long c_lt = 0, c_eq = 0;
  for (int i = threadIdx.x; i < nblk; i += 1024) {
    Blk b = ws->blk[i];
    s_lt += (double)b.sum_lt;
    c_lt += b.cnt_lt; c_eq += b.cnt_eq;
  }
#pragma unroll
  for (int off = 32; off > 0; off >>= 1) {
    s_lt += __shfl_down(s_lt, off);
    c_lt += __shfl_down(c_lt, off);
    c_eq += __shfl_down(c_eq, off);
  }
  __shared__ double rs[16];
  __shared__ unsigned long long rc[16], re[16];
  int wave = threadIdx.x >> 6;
  if ((threadIdx.x & 63) == 0) { rs[wave] = s_lt; rc[wave] = c_lt; re[wave] = c_eq; }
  __syncthreads();
  if (threadIdx.x == 0) {
    double slt = 0.0; unsigned long long clt = 0, ceq = 0;
    for (int w = 0; w < 16; ++w) { slt += rs[w]; clt += rc[w]; ceq += re[w]; }
    slt *= LN2_HI;                        // log2-domain -> ln-domain
    ws->sum_lt = slt; ws->sum_eq = 0.0;   // eq-losses filled by fallback P1 if needed
    ws->cnt_lt = (unsigned)clt; ws->cnt_eq = (unsigned)ceq;
    ws->fin0 = 0u; ws->fin1 = 0u; ws->fin2 = 0u; ws->fin3 = 0u;
    // p_sorted[k] <= 0.7f  <=>  count(p <= 0.7f) > k  => threshold = 0.7f
    if (clt + ceq > (unsigned long long)kidx) {
      out[0] = (float)(slt / (double)clt);
      ws->done = 1u;
    } else {
      ws->done = 0u;
    }
  }
}

// ================= K3: exact fallback, single kernel, spin-synced ===========
// Rare path (threshold > 0.7). NBLK_FB=1024 blocks, 32 KB LDS -> 5 blocks/CU
// -> 1280 co-resident >= 1024: spins cannot deadlock.
__device__ void gsync(unsigned* ctr, unsigned goal) {
  __syncthreads();
  if (threadIdx.x == 0) {
    __threadfence();
    atomicAdd(ctr, 1u);
    while (atomicAdd(ctr, 0u) < goal) __builtin_amdgcn_s_sleep(8);
  }
  __syncthreads();
  __threadfence();
}

__global__ __launch_bounds__(NTHREADS) void k_fallback(
    const float* __restrict__ pred, const float* __restrict__ targ,
    float* __restrict__ out, Ws* __restrict__ ws, int n, int kidx) {
  if (ws->done) return;   // common case: one load per block and out

  __shared__ union {
    struct { unsigned hc[NBINS]; float hs[NBINS]; } l1;
    struct { unsigned sc[NSUB];  float ss[NSUB];  } l2;
  } sh;
  __shared__ float sh_eq;

  const int gtid = blockIdx.x * NTHREADS + threadIdx.x;
  const int gstride = gridDim.x * NTHREADS;

  // ---- P0: zero global fallback arrays ----
  for (int i = gtid; i < NBINS; i += gstride) { ws->Hcnt[i] = 0u; ws->Hsum[i] = 0.f; }
  for (int i = gtid; i < NSUB;  i += gstride) { ws->subCnt[i] = 0u; ws->subSum[i] = 0.f; }
  gsync(&ws->fin0, gridDim.x);

  // ---- P1: level-1 histogram of p > 0.7 (+ eq-loss accumulation) ----
  for (int i = threadIdx.x; i < NBINS; i += NTHREADS) { sh.l1.hc[i] = 0u; sh.l1.hs[i] = 0.f; }
  if (threadIdx.x == 0) sh_eq = 0.f;
  __syncthreads();
  for (int i = gtid; i < n; i += gstride) {
    float pv = pred[i];
    if (pv >= THRESH) {
      float l = bce_loss(pv, targ[i]);
      if (pv == THRESH) {
        atomicAdd(&sh_eq, l);        // eq elements are kept in fallback (thr>0.7)
      } else {
        unsigned b = (__float_as_uint(pv) - BASEU) >> 12;
        if (b > NBINS - 1) b = NBINS - 1;
        atomicAdd(&sh.l1.hc[b], 1u);
        atomicAdd(&sh.l1.hs[b], l);
      }
    }
  }
  __syncthreads();
  for (int i = threadIdx.x; i < NBINS; i += NTHREADS) {
    if (sh.l1.hc[i])        atomicAdd(&ws->Hcnt[i], sh.l1.hc[i]);
    if (sh.l1.hs[i] != 0.f) atomicAdd(&ws->Hsum[i], sh.l1.hs[i]);
  }
  if (threadIdx.x == 0 && sh_eq != 0.f) atomicAdd(&ws->sum_eq, (double)sh_eq);
  gsync(&ws->fin1, gridDim.x);

  // ---- P2: block 0 selects the level-1 bin containing rank kidx ----
  if (blockIdx.x == 0 && threadIdx.x == 0) {
    unsigned long long cum = (unsigned long long)ws->cnt_lt + ws->cnt_eq;
    double csum = ws->sum_lt + ws->sum_eq;
    for (int b = 0; b < NBINS; ++b) {
      unsigned hcnt = atomicAdd(&ws->Hcnt[b], 0u);
      if (cum + hcnt > (unsigned long long)kidx) {
        atomicExch(&ws->selBin, (unsigned)b);
        atomicExch(&ws->rank_r, (unsigned)((unsigned long long)kidx - cum));
        atomicExch(&ws->prefix_cnt, (unsigned)cum);
        ws->prefix_sum = csum;
        break;
      }
      cum  += hcnt;
      csum += (double)atomicAdd(&ws->Hsum[b], 0.f);
    }
  }
  gsync(&ws->fin2, gridDim.x);

  // ---- P3: level-2 exact-pattern histogram within selected bin ----
  unsigned base = BASEU + (atomicAdd(&ws->selBin, 0u) << 12);
  for (int i = threadIdx.x; i < NSUB; i += NTHREADS) { sh.l2.sc[i] = 0u; sh.l2.ss[i] = 0.f; }
  __syncthreads();
  for (int i = gtid; i < n; i += gstride) {
    unsigned u = __float_as_uint(pred[i]);
    if (u >= base && u < base + NSUB) {
      atomicAdd(&sh.l2.sc[u - base], 1u);
      atomicAdd(&sh.l2.ss[u - base], bce_loss(pred[i], targ[i]));
    }
  }
  __syncthreads();
  for (int i = threadIdx.x; i < NSUB; i += NTHREADS) {
    if (sh.l2.sc[i])         atomicAdd(&ws->subCnt[i], sh.l2.sc[i]);
    if (sh.l2.ss[i] != 0.f)  atomicAdd(&ws->subSum[i], sh.l2.ss[i]);
  }
  gsync(&ws->fin3, gridDim.x);

  // ---- P4: block 0 finalizes ----
  if (blockIdx.x == 0 && threadIdx.x == 0) {
    unsigned r = atomicAdd(&ws->rank_r, 0u);
    unsigned long long cum = 0;
    double csum = 0.0;
    for (int i = 0; i < NSUB; ++i) {
      unsigned c = atomicAdd(&ws->subCnt[i], 0u);
      if (cum + c > (unsigned long long)r) {
        unsigned long long cnt_final = (unsigned long long)atomicAdd(&ws->prefix_cnt, 0u) + cum;
        double sum_final = ws->prefix_sum + csum;
        out[0] = (float)(sum_final / (double)cnt_final);
        break;
      }
      cum  += c;
      csum += (double)atomicAdd(&ws->subSum[i], 0.f);
    }
  }
}

extern "C" void kernel_launch(void* const* d_in, const int* in_sizes, int n_in,
                              void* d_out, int out_size, void* d_ws, size_t ws_size,
                              hipStream_t stream) {
  const float* pred = (const float*)d_in[0];
  const float* targ = (const float*)d_in[1];
  float* out = (float*)d_out;
  Ws* ws = (Ws*)d_ws;
  int n = in_sizes[0];
  // min_kept = min(int(0.5*(n-1)), n-1); trunc == floor for positive n
  long long kll = (long long)(n - 1) / 2;
  if (kll > (long long)(n - 1)) kll = n - 1;
  int kidx = (int)kll;

  int nvec = n >> 2;
  int nblk = (nvec + NTHREADS * UNR - 1) / (NTHREADS * UNR);  // 4096 @ n=32M
  if (nblk > MAXBLK) nblk = MAXBLK;
  if (nblk < 1) nblk = 1;

  k_main    <<<nblk, NTHREADS, 0, stream>>>((const f32x4*)pred, (const f32x4*)targ, ws, n);
  k_decide  <<<1, 1024, 0, stream>>>(out, ws, nblk, kidx);
  k_fallback<<<NBLK_FB, NTHREADS, 0, stream>>>(pred, targ, out, ws, n, kidx);
}

// Round 10
// 257.350 us; speedup vs baseline: 1.2475x; 1.0869x over previous
//
#include <hip/hip_runtime.h>

#define THRESH   0.7f
#define BASEU    0x3F333334u   // bit pattern of smallest float > 0.7f
#define NBINS    2048          // level-1 bins: (u-BASEU)>>12  (0.7..1.0 -> 1229 used)
#define NSUB     4096          // level-2: exact patterns within one level-1 bin
#define NTHREADS 256
#define MAXBLK   8192
#define NBLK_FB  1024          // fallback grid; must stay co-resident (spin syncs)
#define LOG2CLAMP 144.2695040888963f   // 100/ln2: clamp in log2 domain
#define LN2_HI   0.6931471805599453    // double, applied once in k_decide

typedef __attribute__((ext_vector_type(4))) float f32x4;

struct Blk { float sum_lt; unsigned cnt_lt, cnt_eq, pad; };  // 16 B

struct Ws {
  Blk      blk[MAXBLK];
  double   sum_lt, sum_eq, prefix_sum;
  unsigned cnt_lt, cnt_eq;
  unsigned done;
  unsigned fin0, fin1, fin2, fin3;
  unsigned selBin, rank_r, prefix_cnt;
  unsigned Hcnt[NBINS];
  float    Hsum[NBINS];
  unsigned subCnt[NSUB];
  float    subSum[NSUB];
};

// t is exactly 0.0 or 1.0 -> BCE collapses to one log; torch clamps log at -100.
// (ln-domain version, used by fallback path only)
__device__ __forceinline__ float bce_loss(float p, float t) {
  float x = (t > 0.5f) ? p : (1.0f - p);
  return fminf(-__logf(x), 100.0f);
}

// =================== K1: R7-proven streaming pass (NT loads) ================
// Grid-stride + __builtin_nontemporal_load (the R6->R7 97->~78us lever:
// read-once data should not allocate in L2/L3). Mild unroll-2 on top.
__global__ void k_main(
    const f32x4* __restrict__ p4, const f32x4* __restrict__ t4,
    Ws* __restrict__ ws, int n) {
  const int nvec = n >> 2;
  const int tid = blockIdx.x * NTHREADS + threadIdx.x;
  const int stride = gridDim.x * NTHREADS;

  float s_lt = 0.f;
  unsigned c_lt = 0u, c_eq = 0u;

#define CONS(PV, TV)                                                           \
  _Pragma("unroll") for (int c = 0; c < 4; ++c) {                              \
    float pv = (PV)[c];                                                        \
    float xx = ((TV)[c] > 0.5f) ? pv : (1.0f - pv);                            \
    float l2 = fminf(-__log2f(xx), LOG2CLAMP);                                 \
    bool lt  = (pv < THRESH);                                                  \
    s_lt += lt ? l2 : 0.0f;                                                    \
    c_lt += lt ? 1u : 0u;                                                      \
    c_eq += (pv == THRESH) ? 1u : 0u;                                          \
  }

  int i = tid;
  // unrolled-by-2: issue 4 NT loads, then consume both pairs
  for (; i + stride < nvec; i += 2 * stride) {
    f32x4 pa = __builtin_nontemporal_load(p4 + i);
    f32x4 pb = __builtin_nontemporal_load(p4 + i + stride);
    f32x4 ta = __builtin_nontemporal_load(t4 + i);
    f32x4 tb = __builtin_nontemporal_load(t4 + i + stride);
    CONS(pa, ta)
    CONS(pb, tb)
  }
  // cleanup (ragged sizes)
  for (; i < nvec; i += stride) {
    f32x4 pa = __builtin_nontemporal_load(p4 + i);
    f32x4 ta = __builtin_nontemporal_load(t4 + i);
    CONS(pa, ta)
  }
#undef CONS
  // scalar tail (n % 4)
  {
    int j = (nvec << 2) + tid;
    if (j < n) {
      float pv = ((const float*)p4)[j];
      float tv = ((const float*)t4)[j];
      float xx = (tv > 0.5f) ? pv : (1.0f - pv);
      float l2 = fminf(-__log2f(xx), LOG2CLAMP);
      if (pv < THRESH)       { c_lt++; s_lt += l2; }
      else if (pv == THRESH) { c_eq++; }
    }
  }

  // wave(64) reduce then block reduce, plain 16-B store (no atomics, no fence)
#pragma unroll
  for (int off = 32; off > 0; off >>= 1) {
    s_lt += __shfl_down(s_lt, off);
    c_lt += __shfl_down(c_lt, off);
    c_eq += __shfl_down(c_eq, off);
  }
  __shared__ float    red_slt[4];
  __shared__ unsigned red_clt[4], red_ceq[4];
  int wave = threadIdx.x >> 6;
  if ((threadIdx.x & 63) == 0) {
    red_slt[wave] = s_lt; red_clt[wave] = c_lt; red_ceq[wave] = c_eq;
  }
  __syncthreads();
  if (threadIdx.x == 0) {
    Blk b;
    b.sum_lt = red_slt[0] + red_slt[1] + red_slt[2] + red_slt[3];
    b.cnt_lt = red_clt[0] + red_clt[1] + red_clt[2] + red_clt[3];
    b.cnt_eq = red_ceq[0] + red_ceq[1] + red_ceq[2] + red_ceq[3];
    b.pad = 0u;
    ws->blk[blockIdx.x] = b;
  }
}

// ======= K2: cross-block reduce + decision + fallback-counter init ==========
__global__ __launch_bounds__(1024) void k_decide(
    float* __restrict__ out, Ws* __restrict__ ws, int nblk, int kidx) {
  double s_lt = 0.0;
  unsigned long long c_lt = 0, c_eq = 0;
  for (int i = threadIdx.x; i < nblk; i += 1024) {
    Blk b = ws->blk[i];
    s_lt += (double)b.sum_lt;
    c_lt += b.cnt_lt; c_eq += b.cnt_eq;
  }
#pragma unroll
  for (int off = 32; off > 0; off >>= 1) {
    s_lt += __shfl_down(s_lt, off);
    c_lt += __shfl_down(c_lt, off);
    c_eq += __shfl_down(c_eq, off);
  }
  __shared__ double rs[16];
  __shared__ unsigned long long rc[16], re[16];
  int wave = threadIdx.x >> 6;
  if ((threadIdx.x & 63) == 0) { rs[wave] = s_lt; rc[wave] = c_lt; re[wave] = c_eq; }
  __syncthreads();
  if (threadIdx.x == 0) {
    double slt = 0.0; unsigned long long clt = 0, ceq = 0;
    for (int w = 0; w < 16; ++w) { slt += rs[w]; clt += rc[w]; ceq += re[w]; }
    slt *= LN2_HI;                        // log2-domain -> ln-domain
    ws->sum_lt = slt; ws->sum_eq = 0.0;   // eq-losses filled by fallback P1 if needed
    ws->cnt_lt = (unsigned)clt; ws->cnt_eq = (unsigned)ceq;
    ws->fin0 = 0u; ws->fin1 = 0u; ws->fin2 = 0u; ws->fin3 = 0u;
    // p_sorted[k] <= 0.7f  <=>  count(p <= 0.7f) > k  => threshold = 0.7f
    if (clt + ceq > (unsigned long long)kidx) {
      out[0] = (float)(slt / (double)clt);
      ws->done = 1u;
    } else {
      ws->done = 0u;
    }
  }
}

// ================= K3: exact fallback, single kernel, spin-synced ===========
// Rare path (threshold > 0.7). NBLK_FB=1024 blocks, 32 KB LDS -> 5 blocks/CU
// -> 1280 co-resident >= 1024: spins cannot deadlock.
__device__ void gsync(unsigned* ctr, unsigned goal) {
  __syncthreads();
  if (threadIdx.x == 0) {
    __threadfence();
    atomicAdd(ctr, 1u);
    while (atomicAdd(ctr, 0u) < goal) __builtin_amdgcn_s_sleep(8);
  }
  __syncthreads();
  __threadfence();
}

__global__ __launch_bounds__(NTHREADS) void k_fallback(
    const float* __restrict__ pred, const float* __restrict__ targ,
    float* __restrict__ out, Ws* __restrict__ ws, int n, int kidx) {
  if (ws->done) return;   // common case: one load per block and out

  __shared__ union {
    struct { unsigned hc[NBINS]; float hs[NBINS]; } l1;
    struct { unsigned sc[NSUB];  float ss[NSUB];  } l2;
  } sh;
  __shared__ float sh_eq;

  const int gtid = blockIdx.x * NTHREADS + threadIdx.x;
  const int gstride = gridDim.x * NTHREADS;

  // ---- P0: zero global fallback arrays ----
  for (int i = gtid; i < NBINS; i += gstride) { ws->Hcnt[i] = 0u; ws->Hsum[i] = 0.f; }
  for (int i = gtid; i < NSUB;  i += gstride) { ws->subCnt[i] = 0u; ws->subSum[i] = 0.f; }
  gsync(&ws->fin0, gridDim.x);

  // ---- P1: level-1 histogram of p > 0.7 (+ eq-loss accumulation) ----
  for (int i = threadIdx.x; i < NBINS; i += NTHREADS) { sh.l1.hc[i] = 0u; sh.l1.hs[i] = 0.f; }
  if (threadIdx.x == 0) sh_eq = 0.f;
  __syncthreads();
  for (int i = gtid; i < n; i += gstride) {
    float pv = pred[i];
    if (pv >= THRESH) {
      float l = bce_loss(pv, targ[i]);
      if (pv == THRESH) {
        atomicAdd(&sh_eq, l);        // eq elements are kept in fallback (thr>0.7)
      } else {
        unsigned b = (__float_as_uint(pv) - BASEU) >> 12;
        if (b > NBINS - 1) b = NBINS - 1;
        atomicAdd(&sh.l1.hc[b], 1u);
        atomicAdd(&sh.l1.hs[b], l);
      }
    }
  }
  __syncthreads();
  for (int i = threadIdx.x; i < NBINS; i += NTHREADS) {
    if (sh.l1.hc[i])        atomicAdd(&ws->Hcnt[i], sh.l1.hc[i]);
    if (sh.l1.hs[i] != 0.f) atomicAdd(&ws->Hsum[i], sh.l1.hs[i]);
  }
  if (threadIdx.x == 0 && sh_eq != 0.f) atomicAdd(&ws->sum_eq, (double)sh_eq);
  gsync(&ws->fin1, gridDim.x);

  // ---- P2: block 0 selects the level-1 bin containing rank kidx ----
  if (blockIdx.x == 0 && threadIdx.x == 0) {
    unsigned long long cum = (unsigned long long)ws->cnt_lt + ws->cnt_eq;
    double csum = ws->sum_lt + ws->sum_eq;
    for (int b = 0; b < NBINS; ++b) {
      unsigned hcnt = atomicAdd(&ws->Hcnt[b], 0u);
      if (cum + hcnt > (unsigned long long)kidx) {
        atomicExch(&ws->selBin, (unsigned)b);
        atomicExch(&ws->rank_r, (unsigned)((unsigned long long)kidx - cum));
        atomicExch(&ws->prefix_cnt, (unsigned)cum);
        ws->prefix_sum = csum;
        break;
      }
      cum  += hcnt;
      csum += (double)atomicAdd(&ws->Hsum[b], 0.f);
    }
  }
  gsync(&ws->fin2, gridDim.x);

  // ---- P3: level-2 exact-pattern histogram within selected bin ----
  unsigned base = BASEU + (atomicAdd(&ws->selBin, 0u) << 12);
  for (int i = threadIdx.x; i < NSUB; i += NTHREADS) { sh.l2.sc[i] = 0u; sh.l2.ss[i] = 0.f; }
  __syncthreads();
  for (int i = gtid; i < n; i += gstride) {
    unsigned u = __float_as_uint(pred[i]);
    if (u >= base && u < base + NSUB) {
      atomicAdd(&sh.l2.sc[u - base], 1u);
      atomicAdd(&sh.l2.ss[u - base], bce_loss(pred[i], targ[i]));
    }
  }
  __syncthreads();
  for (int i = threadIdx.x; i < NSUB; i += NTHREADS) {
    if (sh.l2.sc[i])         atomicAdd(&ws->subCnt[i], sh.l2.sc[i]);
    if (sh.l2.ss[i] != 0.f)  atomicAdd(&ws->subSum[i], sh.l2.ss[i]);
  }
  gsync(&ws->fin3, gridDim.x);

  // ---- P4: block 0 finalizes ----
  if (blockIdx.x == 0 && threadIdx.x == 0) {
    unsigned r = atomicAdd(&ws->rank_r, 0u);
    unsigned long long cum = 0;
    double csum = 0.0;
    for (int i = 0; i < NSUB; ++i) {
      unsigned c = atomicAdd(&ws->subCnt[i], 0u);
      if (cum + c > (unsigned long long)r) {
        unsigned long long cnt_final = (unsigned long long)atomicAdd(&ws->prefix_cnt, 0u) + cum;
        double sum_final = ws->prefix_sum + csum;
        out[0] = (float)(sum_final / (double)cnt_final);
        break;
      }
      cum  += c;
      csum += (double)atomicAdd(&ws->subSum[i], 0.f);
    }
  }
}

extern "C" void kernel_launch(void* const* d_in, const int* in_sizes, int n_in,
                              void* d_out, int out_size, void* d_ws, size_t ws_size,
                              hipStream_t stream) {
  const float* pred = (const float*)d_in[0];
  const float* targ = (const float*)d_in[1];
  float* out = (float*)d_out;
  Ws* ws = (Ws*)d_ws;
  int n = in_sizes[0];
  // min_kept = min(int(0.5*(n-1)), n-1); trunc == floor for positive n
  long long kll = (long long)(n - 1) / 2;
  if (kll > (long long)(n - 1)) kll = n - 1;
  int kidx = (int)kll;

  int nvec = n >> 2;
  int nblk = (nvec + NTHREADS - 1) / NTHREADS;
  if (nblk > MAXBLK) nblk = MAXBLK;   // 8192 @ n=33.5M
  if (nblk < 1) nblk = 1;

  k_main    <<<nblk, NTHREADS, 0, stream>>>((const f32x4*)pred, (const f32x4*)targ, ws, n);
  k_decide  <<<1, 1024, 0, stream>>>(out, ws, nblk, kidx);
  k_fallback<<<NBLK_FB, NTHREADS, 0, stream>>>(pred, targ, out, ws, n, kidx);
}